// Round 3
// baseline (161.088 us; speedup 1.0000x reference)
//
#include <hip/hip_runtime.h>
#include <hip/hip_bf16.h>
#include <math.h>

typedef __bf16 bf16_t;
typedef __bf16 bf16x8 __attribute__((ext_vector_type(8)));
typedef float f32x4 __attribute__((ext_vector_type(4)));

#define N2 4096
#define NHALF 2048
#define DIM 512
#define TEMP_INV 2.0f   // 1/TEMPERATURE
#define NBLK 1056       // number of (i,j) cells, j >= 2i, i<32, j<64

// ---------------------------------------------------------------------------
// Kernel 1 (fused prep): one wave per row-PAIR (i, i+N). Normalize both rows
// to bf16, pos[i]=pos[p] (symmetric), diag from bf16-rounded values, zero
// rowsum slice + completion counter.
// ---------------------------------------------------------------------------
__global__ __launch_bounds__(256) void k_prep(const float* __restrict__ x,
                                              bf16_t* __restrict__ xn,
                                              float* __restrict__ pos,
                                              float* __restrict__ diag,
                                              float* __restrict__ rowsum,
                                              unsigned int* __restrict__ counter) {
    const int pair = blockIdx.x * 4 + (threadIdx.x >> 6);   // 0..2047
    const int lane = threadIdx.x & 63;
    const int rowi = pair;
    const int rowp = pair + NHALF;

    const float4* xi = reinterpret_cast<const float4*>(x + (size_t)rowi * DIM);
    const float4* xp = reinterpret_cast<const float4*>(x + (size_t)rowp * DIM);
    float4 a0 = xi[lane * 2], a1 = xi[lane * 2 + 1];
    float4 b0 = xp[lane * 2], b1 = xp[lane * 2 + 1];

    float ssi = a0.x*a0.x + a0.y*a0.y + a0.z*a0.z + a0.w*a0.w
              + a1.x*a1.x + a1.y*a1.y + a1.z*a1.z + a1.w*a1.w;
    float ssp = b0.x*b0.x + b0.y*b0.y + b0.z*b0.z + b0.w*b0.w
              + b1.x*b1.x + b1.y*b1.y + b1.z*b1.z + b1.w*b1.w;
    float dot = a0.x*b0.x + a0.y*b0.y + a0.z*b0.z + a0.w*b0.w
              + a1.x*b1.x + a1.y*b1.y + a1.z*b1.z + a1.w*b1.w;
#pragma unroll
    for (int off = 32; off; off >>= 1) {
        ssi += __shfl_xor(ssi, off, 64);
        ssp += __shfl_xor(ssp, off, 64);
        dot += __shfl_xor(dot, off, 64);
    }
    const float sci = 1.0f / fmaxf(sqrtf(ssi), 1e-8f);
    const float scp = 1.0f / fmaxf(sqrtf(ssp), 1e-8f);

    float va[8] = {a0.x, a0.y, a0.z, a0.w, a1.x, a1.y, a1.z, a1.w};
    float vb[8] = {b0.x, b0.y, b0.z, b0.w, b1.x, b1.y, b1.z, b1.w};
    bf16x8 oi, op;
    float dii = 0.0f, dpp = 0.0f;
#pragma unroll
    for (int t = 0; t < 8; ++t) {
        oi[t] = (bf16_t)(va[t] * sci);
        op[t] = (bf16_t)(vb[t] * scp);
        float fi = (float)oi[t], fp_ = (float)op[t];
        dii += fi * fi;
        dpp += fp_ * fp_;
    }
    *reinterpret_cast<bf16x8*>(xn + (size_t)rowi * DIM + lane * 8) = oi;
    *reinterpret_cast<bf16x8*>(xn + (size_t)rowp * DIM + lane * 8) = op;
#pragma unroll
    for (int off = 32; off; off >>= 1) {
        dii += __shfl_xor(dii, off, 64);
        dpp += __shfl_xor(dpp, off, 64);
    }
    if (lane == 0) {
        const float pv = TEMP_INV * dot * sci * scp;
        pos[rowi] = pv;
        pos[rowp] = pv;
        diag[rowi] = TEMP_INV * dii;
        diag[rowp] = TEMP_INV * dpp;
    }
    if (threadIdx.x < 8) rowsum[blockIdx.x * 8 + threadIdx.x] = 0.0f;
    if (blockIdx.x == 0 && threadIdx.x == 8) *counter = 0u;
}

// ---------------------------------------------------------------------------
// Kernel 2: symmetric sim-GEMM over 128x64 cells (j >= 2i), BK=32,
// mfma 16x16x32 bf16, global_load_lds width-16 staging. Cells j in
// {2i, 2i+1} together form the diagonal 128-tile -> rowsum only; cells
// j >= 2i+2 are strictly above the diagonal -> rowsum + colsum.
// Last finished block computes the final loss (fence + agent-scope counter).
// ---------------------------------------------------------------------------
__device__ __forceinline__ void load_lds16(const bf16_t* g, bf16_t* l) {
    __builtin_amdgcn_global_load_lds(
        (const __attribute__((address_space(1))) unsigned int*)g,
        (__attribute__((address_space(3))) unsigned int*)l,
        16, 0, 0);
}

__global__ __launch_bounds__(256, 4) void k_simgemm(const bf16_t* __restrict__ xn,
                                                    float* __restrict__ rowsum,
                                                    const float* __restrict__ pos,
                                                    const float* __restrict__ diag,
                                                    unsigned int* __restrict__ counter,
                                                    float* __restrict__ out) {
    __shared__ bf16_t As[128 * 32];   // 8 KB
    __shared__ bf16_t Bs[64 * 32];    // 4 KB
    __shared__ float  rpA[128];
    __shared__ float  rpB[64];
    __shared__ float  red[256];
    __shared__ int    lastFlag;

    // unrank blockIdx.x -> (i, j) with C(i) = i*(65-i)
    const int t = blockIdx.x;
    int i = (int)((65.0f - sqrtf(4225.0f - 4.0f * (float)t)) * 0.5f);
    while (i * (65 - i) > t) --i;
    while ((i + 1) * (64 - i) <= t) ++i;
    const int j = 2 * i + (t - i * (65 - i));
    const bool diagc = (j <= 2 * i + 1);

    const int tid  = threadIdx.x;
    const int lane = tid & 63;
    const int wid  = tid >> 6;
    const int wr   = wid >> 1;   // 0..1: 64-row half
    const int wc   = wid & 1;    // 0..1: 32-col half
    const int q    = lane >> 4;
    const int l15  = lane & 15;

    if (tid < 128) rpA[tid] = 0.0f;
    if (tid < 64)  rpB[tid] = 0.0f;

    const int sRow = tid >> 2;          // 0..63
    const int sCol = (tid & 3) * 8;
    const bf16_t* gA0 = xn + (size_t)(i * 128 + sRow) * DIM + sCol;
    const bf16_t* gB0 = xn + (size_t)(j * 64 + sRow) * DIM + sCol;
    bf16_t* lA0 = &As[tid * 8];
    bf16_t* lA1 = &As[2048 + tid * 8];
    bf16_t* lB0 = &Bs[tid * 8];

    f32x4 acc[4][2] = {};

    for (int k0 = 0; k0 < DIM; k0 += 32) {
        __syncthreads();
        load_lds16(gA0 + k0, lA0);
        load_lds16(gA0 + (size_t)64 * DIM + k0, lA1);
        load_lds16(gB0 + k0, lB0);
        __syncthreads();

        bf16x8 af[4], bfv[2];
#pragma unroll
        for (int mt = 0; mt < 4; ++mt)
            af[mt] = *reinterpret_cast<const bf16x8*>(
                &As[(wr * 64 + mt * 16 + l15) * 32 + q * 8]);
#pragma unroll
        for (int nt = 0; nt < 2; ++nt)
            bfv[nt] = *reinterpret_cast<const bf16x8*>(
                &Bs[(wc * 32 + nt * 16 + l15) * 32 + q * 8]);
#pragma unroll
        for (int mt = 0; mt < 4; ++mt)
#pragma unroll
            for (int nt = 0; nt < 2; ++nt)
                acc[mt][nt] = __builtin_amdgcn_mfma_f32_16x16x32_bf16(
                    af[mt], bfv[nt], acc[mt][nt], 0, 0, 0);
    }

    // Epilogue. C/D: row = wr*64+mt*16+q*4+r, col = wc*32+nt*16+l15.
    float colacc[2] = {0.0f, 0.0f};
#pragma unroll
    for (int mt = 0; mt < 4; ++mt) {
        float rowp[4] = {0.0f, 0.0f, 0.0f, 0.0f};
#pragma unroll
        for (int nt = 0; nt < 2; ++nt)
#pragma unroll
            for (int r = 0; r < 4; ++r) {
                float e = __expf(TEMP_INV * acc[mt][nt][r]);
                rowp[r] += e;
                colacc[nt] += e;
            }
#pragma unroll
        for (int r = 0; r < 4; ++r) {
            float p = rowp[r];
            p += __shfl_xor(p, 1, 64);
            p += __shfl_xor(p, 2, 64);
            p += __shfl_xor(p, 4, 64);
            p += __shfl_xor(p, 8, 64);
            if (l15 == 0) atomicAdd(&rpA[wr * 64 + mt * 16 + q * 4 + r], p);
        }
    }
    if (!diagc) {
#pragma unroll
        for (int nt = 0; nt < 2; ++nt) {
            float c = colacc[nt];
            c += __shfl_xor(c, 16, 64);
            c += __shfl_xor(c, 32, 64);
            if (q == 0) atomicAdd(&rpB[wc * 32 + nt * 16 + l15], c);
        }
    }
    __syncthreads();
    if (tid < 128) {
        atomicAdd(&rowsum[i * 128 + tid], rpA[tid]);
    } else if (!diagc && tid < 192) {
        atomicAdd(&rowsum[j * 64 + (tid - 128)], rpB[tid - 128]);
    }

    // ---- last-block finalize ----
    __threadfence();
    __syncthreads();
    if (tid == 0) {
        unsigned int done = __hip_atomic_fetch_add(counter, 1u, __ATOMIC_ACQ_REL,
                                                   __HIP_MEMORY_SCOPE_AGENT);
        lastFlag = (done == (unsigned int)(gridDim.x - 1)) ? 1 : 0;
    }
    __syncthreads();
    if (lastFlag) {
        __threadfence();
        float s = 0.0f;
        for (int r = tid; r < N2; r += 256) {
            float S = __hip_atomic_load(&rowsum[r], __ATOMIC_RELAXED,
                                        __HIP_MEMORY_SCOPE_AGENT);
            s += __logf(S - __expf(diag[r])) - pos[r];
        }
        red[tid] = s;
        __syncthreads();
        for (int st = 128; st; st >>= 1) {
            if (tid < st) red[tid] += red[tid + st];
            __syncthreads();
        }
        if (tid == 0) out[0] = red[0] / (float)N2;
    }
}

// ---------------------------------------------------------------------------
extern "C" void kernel_launch(void* const* d_in, const int* in_sizes, int n_in,
                              void* d_out, int out_size, void* d_ws, size_t ws_size,
                              hipStream_t stream) {
    (void)in_sizes; (void)n_in; (void)out_size; (void)ws_size;
    const float* x = (const float*)d_in[0];
    float* out = (float*)d_out;

    char* ws = (char*)d_ws;
    bf16_t* xn     = (bf16_t*)ws;                          // 4 MB
    float*  rowsum = (float*)(ws + (size_t)N2 * DIM * 2);  // 16 KB
    float*  pos    = rowsum + N2;
    float*  diag   = pos + N2;
    unsigned int* counter = (unsigned int*)(diag + N2);

    k_prep<<<512, 256, 0, stream>>>(x, xn, pos, diag, rowsum, counter);
    k_simgemm<<<NBLK, 256, 0, stream>>>(xn, rowsum, pos, diag, counter, out);
}

// Round 4
// 112.220 us; speedup vs baseline: 1.4355x; 1.4355x over previous
//
#include <hip/hip_runtime.h>
#include <hip/hip_bf16.h>
#include <math.h>

typedef __bf16 bf16_t;
typedef __bf16 bf16x8 __attribute__((ext_vector_type(8)));
typedef float f32x4 __attribute__((ext_vector_type(4)));

#define N2 4096
#define NHALF 2048
#define DIM 512
#define TEMP_INV 2.0f   // 1/TEMPERATURE

// ---------------------------------------------------------------------------
// Kernel 1 (fused prep): one wave per row-PAIR (i, i+N). Normalize both rows
// to bf16, pos[i]=pos[p] (symmetric), diag from bf16-rounded values, zero
// rowsum slice.
// ---------------------------------------------------------------------------
__global__ __launch_bounds__(256) void k_prep(const float* __restrict__ x,
                                              bf16_t* __restrict__ xn,
                                              float* __restrict__ pos,
                                              float* __restrict__ diag,
                                              float* __restrict__ rowsum) {
    const int pair = blockIdx.x * 4 + (threadIdx.x >> 6);   // 0..2047
    const int lane = threadIdx.x & 63;
    const int rowi = pair;
    const int rowp = pair + NHALF;

    const float4* xi = reinterpret_cast<const float4*>(x + (size_t)rowi * DIM);
    const float4* xp = reinterpret_cast<const float4*>(x + (size_t)rowp * DIM);
    float4 a0 = xi[lane * 2], a1 = xi[lane * 2 + 1];
    float4 b0 = xp[lane * 2], b1 = xp[lane * 2 + 1];

    float ssi = a0.x*a0.x + a0.y*a0.y + a0.z*a0.z + a0.w*a0.w
              + a1.x*a1.x + a1.y*a1.y + a1.z*a1.z + a1.w*a1.w;
    float ssp = b0.x*b0.x + b0.y*b0.y + b0.z*b0.z + b0.w*b0.w
              + b1.x*b1.x + b1.y*b1.y + b1.z*b1.z + b1.w*b1.w;
    float dot = a0.x*b0.x + a0.y*b0.y + a0.z*b0.z + a0.w*b0.w
              + a1.x*b1.x + a1.y*b1.y + a1.z*b1.z + a1.w*b1.w;
#pragma unroll
    for (int off = 32; off; off >>= 1) {
        ssi += __shfl_xor(ssi, off, 64);
        ssp += __shfl_xor(ssp, off, 64);
        dot += __shfl_xor(dot, off, 64);
    }
    const float sci = 1.0f / fmaxf(sqrtf(ssi), 1e-8f);
    const float scp = 1.0f / fmaxf(sqrtf(ssp), 1e-8f);

    float va[8] = {a0.x, a0.y, a0.z, a0.w, a1.x, a1.y, a1.z, a1.w};
    float vb[8] = {b0.x, b0.y, b0.z, b0.w, b1.x, b1.y, b1.z, b1.w};
    bf16x8 oi, op;
    float dii = 0.0f, dpp = 0.0f;
#pragma unroll
    for (int t = 0; t < 8; ++t) {
        oi[t] = (bf16_t)(va[t] * sci);
        op[t] = (bf16_t)(vb[t] * scp);
        float fi = (float)oi[t], fp_ = (float)op[t];
        dii += fi * fi;
        dpp += fp_ * fp_;
    }
    *reinterpret_cast<bf16x8*>(xn + (size_t)rowi * DIM + lane * 8) = oi;
    *reinterpret_cast<bf16x8*>(xn + (size_t)rowp * DIM + lane * 8) = op;
#pragma unroll
    for (int off = 32; off; off >>= 1) {
        dii += __shfl_xor(dii, off, 64);
        dpp += __shfl_xor(dpp, off, 64);
    }
    if (lane == 0) {
        const float pv = TEMP_INV * dot * sci * scp;
        pos[rowi] = pv;
        pos[rowp] = pv;
        diag[rowi] = TEMP_INV * dii;
        diag[rowp] = TEMP_INV * dpp;
    }
    if (threadIdx.x < 8) rowsum[blockIdx.x * 8 + threadIdx.x] = 0.0f;
}

// ---------------------------------------------------------------------------
// Kernel 2: symmetric sim-GEMM, upper-triangle 128x128 blocks (528), NO LDS
// staging: MFMA fragments loaded directly global->register. One
// global_load_dwordx4 per fragment = 16 rows x one fully-consumed 64B line
// (A-frag layout A[m=lane&15][k=(lane>>4)*8+j]). No per-K barriers at all;
// 2-stage register pipeline lets loads overlap MFMA via partial vmcnt.
// Epilogue: exp + row sums (and col sums for off-diagonal blocks).
// ---------------------------------------------------------------------------
__global__ __launch_bounds__(256) void k_simgemm(const bf16_t* __restrict__ xn,
                                                 float* __restrict__ rowsum) {
    __shared__ float rpA[128];
    __shared__ float rpB[128];

    // unrank blockIdx.x -> (bm <= bn) upper-triangle pair
    const int t = blockIdx.x;
    int bn = (int)((sqrtf(8.0f * (float)t + 1.0f) - 1.0f) * 0.5f);
    while ((bn * (bn + 1)) / 2 > t) --bn;
    while (((bn + 1) * (bn + 2)) / 2 <= t) ++bn;
    const int bm = t - (bn * (bn + 1)) / 2;
    const bool diagb = (bm == bn);

    const int tid  = threadIdx.x;
    const int lane = tid & 63;
    const int wid  = tid >> 6;
    const int wr   = wid >> 1;   // wave row half
    const int wc   = wid & 1;    // wave col half
    const int q    = lane >> 4;
    const int l15  = lane & 15;

    if (tid < 128) { rpA[tid] = 0.0f; rpB[tid] = 0.0f; }

    // per-lane fragment base: row (tileBase + l15), col q*8
    const bf16_t* Ab = xn + (size_t)(bm * 128 + wr * 64 + l15) * DIM + q * 8;
    const bf16_t* Bb = xn + (size_t)(bn * 128 + wc * 64 + l15) * DIM + q * 8;

    f32x4 acc[4][4] = {};
    bf16x8 a0[4], b0[4], a1[4], b1[4];

#pragma unroll
    for (int mt = 0; mt < 4; ++mt) {
        a0[mt] = *reinterpret_cast<const bf16x8*>(Ab + (size_t)(mt * 16) * DIM);
        b0[mt] = *reinterpret_cast<const bf16x8*>(Bb + (size_t)(mt * 16) * DIM);
    }

    for (int k0 = 0; k0 < DIM; k0 += 64) {
        // prefetch k0+32 while computing k0
#pragma unroll
        for (int mt = 0; mt < 4; ++mt) {
            a1[mt] = *reinterpret_cast<const bf16x8*>(Ab + (size_t)(mt * 16) * DIM + k0 + 32);
            b1[mt] = *reinterpret_cast<const bf16x8*>(Bb + (size_t)(mt * 16) * DIM + k0 + 32);
        }
#pragma unroll
        for (int mt = 0; mt < 4; ++mt)
#pragma unroll
            for (int nt = 0; nt < 4; ++nt)
                acc[mt][nt] = __builtin_amdgcn_mfma_f32_16x16x32_bf16(
                    a0[mt], b0[nt], acc[mt][nt], 0, 0, 0);
        // prefetch k0+64 while computing k0+32
        if (k0 + 64 < DIM) {
#pragma unroll
            for (int mt = 0; mt < 4; ++mt) {
                a0[mt] = *reinterpret_cast<const bf16x8*>(Ab + (size_t)(mt * 16) * DIM + k0 + 64);
                b0[mt] = *reinterpret_cast<const bf16x8*>(Bb + (size_t)(mt * 16) * DIM + k0 + 64);
            }
        }
#pragma unroll
        for (int mt = 0; mt < 4; ++mt)
#pragma unroll
            for (int nt = 0; nt < 4; ++nt)
                acc[mt][nt] = __builtin_amdgcn_mfma_f32_16x16x32_bf16(
                    a1[mt], b1[nt], acc[mt][nt], 0, 0, 0);
    }

    __syncthreads();  // rpA/rpB zero-init visible

    // Epilogue. C/D: row = wr*64+mt*16+q*4+r, col = wc*64+nt*16+l15.
    float colacc[4] = {0.0f, 0.0f, 0.0f, 0.0f};
#pragma unroll
    for (int mt = 0; mt < 4; ++mt) {
        float rowp[4] = {0.0f, 0.0f, 0.0f, 0.0f};
#pragma unroll
        for (int nt = 0; nt < 4; ++nt)
#pragma unroll
            for (int r = 0; r < 4; ++r) {
                float e = __expf(TEMP_INV * acc[mt][nt][r]);
                rowp[r] += e;
                colacc[nt] += e;
            }
#pragma unroll
        for (int r = 0; r < 4; ++r) {
            float p = rowp[r];
            p += __shfl_xor(p, 1, 64);
            p += __shfl_xor(p, 2, 64);
            p += __shfl_xor(p, 4, 64);
            p += __shfl_xor(p, 8, 64);
            if (l15 == 0) atomicAdd(&rpA[wr * 64 + mt * 16 + q * 4 + r], p);
        }
    }
    if (!diagb) {
#pragma unroll
        for (int nt = 0; nt < 4; ++nt) {
            float c = colacc[nt];
            c += __shfl_xor(c, 16, 64);
            c += __shfl_xor(c, 32, 64);
            if (q == 0) atomicAdd(&rpB[wc * 64 + nt * 16 + l15], c);
        }
    }
    __syncthreads();
    if (tid < 128) {
        atomicAdd(&rowsum[bm * 128 + tid], rpA[tid]);
    } else if (!diagb) {
        atomicAdd(&rowsum[bn * 128 + (tid - 128)], rpB[tid - 128]);
    }
}

// ---------------------------------------------------------------------------
// Kernel 3: loss = mean_i( log(S_i - exp(diag_i)) - pos_i )
// ---------------------------------------------------------------------------
__global__ __launch_bounds__(256) void k_finalize(const float* __restrict__ rowsum,
                                                  const float* __restrict__ pos,
                                                  const float* __restrict__ diag,
                                                  float* __restrict__ out) {
    __shared__ float red[256];
    float s = 0.0f;
    for (int i = threadIdx.x; i < N2; i += 256)
        s += __logf(rowsum[i] - __expf(diag[i])) - pos[i];
    red[threadIdx.x] = s;
    __syncthreads();
    for (int st = 128; st; st >>= 1) {
        if (threadIdx.x < st) red[threadIdx.x] += red[threadIdx.x + st];
        __syncthreads();
    }
    if (threadIdx.x == 0) out[0] = red[0] / (float)N2;
}

// ---------------------------------------------------------------------------
extern "C" void kernel_launch(void* const* d_in, const int* in_sizes, int n_in,
                              void* d_out, int out_size, void* d_ws, size_t ws_size,
                              hipStream_t stream) {
    (void)in_sizes; (void)n_in; (void)out_size; (void)ws_size;
    const float* x = (const float*)d_in[0];
    float* out = (float*)d_out;

    char* ws = (char*)d_ws;
    bf16_t* xn     = (bf16_t*)ws;                          // 4 MB
    float*  rowsum = (float*)(ws + (size_t)N2 * DIM * 2);  // 16 KB
    float*  pos    = rowsum + N2;
    float*  diag   = pos + N2;

    k_prep<<<512, 256, 0, stream>>>(x, xn, pos, diag, rowsum);
    k_simgemm<<<528, 256, 0, stream>>>(xn, rowsum);
    k_finalize<<<1, 256, 0, stream>>>(rowsum, pos, diag, out);
}

// Round 5
// 88.040 us; speedup vs baseline: 1.8297x; 1.2747x over previous
//
#include <hip/hip_runtime.h>
#include <hip/hip_bf16.h>
#include <math.h>

typedef __bf16 bf16_t;
typedef __bf16 bf16x8 __attribute__((ext_vector_type(8)));
typedef float f32x4 __attribute__((ext_vector_type(4)));

#define N2 4096
#define NHALF 2048
#define DIM 512
#define TEMP_INV 2.0f   // 1/TEMPERATURE

// ---------------------------------------------------------------------------
// Kernel 1 (fused prep): one wave per row-PAIR (i, i+N). Normalize both rows
// to bf16, pos[i]=pos[p] (symmetric), diag from bf16-rounded values, zero
// rowsum slice.
// ---------------------------------------------------------------------------
__global__ __launch_bounds__(256) void k_prep(const float* __restrict__ x,
                                              bf16_t* __restrict__ xn,
                                              float* __restrict__ pos,
                                              float* __restrict__ diag,
                                              float* __restrict__ rowsum) {
    const int pair = blockIdx.x * 4 + (threadIdx.x >> 6);   // 0..2047
    const int lane = threadIdx.x & 63;
    const int rowi = pair;
    const int rowp = pair + NHALF;

    const float4* xi = reinterpret_cast<const float4*>(x + (size_t)rowi * DIM);
    const float4* xp = reinterpret_cast<const float4*>(x + (size_t)rowp * DIM);
    float4 a0 = xi[lane * 2], a1 = xi[lane * 2 + 1];
    float4 b0 = xp[lane * 2], b1 = xp[lane * 2 + 1];

    float ssi = a0.x*a0.x + a0.y*a0.y + a0.z*a0.z + a0.w*a0.w
              + a1.x*a1.x + a1.y*a1.y + a1.z*a1.z + a1.w*a1.w;
    float ssp = b0.x*b0.x + b0.y*b0.y + b0.z*b0.z + b0.w*b0.w
              + b1.x*b1.x + b1.y*b1.y + b1.z*b1.z + b1.w*b1.w;
    float dot = a0.x*b0.x + a0.y*b0.y + a0.z*b0.z + a0.w*b0.w
              + a1.x*b1.x + a1.y*b1.y + a1.z*b1.z + a1.w*b1.w;
#pragma unroll
    for (int off = 32; off; off >>= 1) {
        ssi += __shfl_xor(ssi, off, 64);
        ssp += __shfl_xor(ssp, off, 64);
        dot += __shfl_xor(dot, off, 64);
    }
    const float sci = 1.0f / fmaxf(sqrtf(ssi), 1e-8f);
    const float scp = 1.0f / fmaxf(sqrtf(ssp), 1e-8f);

    float va[8] = {a0.x, a0.y, a0.z, a0.w, a1.x, a1.y, a1.z, a1.w};
    float vb[8] = {b0.x, b0.y, b0.z, b0.w, b1.x, b1.y, b1.z, b1.w};
    bf16x8 oi, op;
    float dii = 0.0f, dpp = 0.0f;
#pragma unroll
    for (int t = 0; t < 8; ++t) {
        oi[t] = (bf16_t)(va[t] * sci);
        op[t] = (bf16_t)(vb[t] * scp);
        float fi = (float)oi[t], fp_ = (float)op[t];
        dii += fi * fi;
        dpp += fp_ * fp_;
    }
    *reinterpret_cast<bf16x8*>(xn + (size_t)rowi * DIM + lane * 8) = oi;
    *reinterpret_cast<bf16x8*>(xn + (size_t)rowp * DIM + lane * 8) = op;
#pragma unroll
    for (int off = 32; off; off >>= 1) {
        dii += __shfl_xor(dii, off, 64);
        dpp += __shfl_xor(dpp, off, 64);
    }
    if (lane == 0) {
        const float pv = TEMP_INV * dot * sci * scp;
        pos[rowi] = pv;
        pos[rowp] = pv;
        diag[rowi] = TEMP_INV * dii;
        diag[rowp] = TEMP_INV * dpp;
    }
    if (threadIdx.x < 8) rowsum[blockIdx.x * 8 + threadIdx.x] = 0.0f;
}

// ---------------------------------------------------------------------------
// Kernel 2: symmetric sim-GEMM, upper-triangle 128x128 blocks (528 = 2.06/CU),
// BK=128 (only 4 K-iters -> 4 barrier drains instead of 16; 64 KB LDS is free
// because we're grid-limited to 2 blocks/CU anyway). XOR k-chunk swizzle
// (chunk ^ row%16) breaks the 16-way bank conflict of the 256 B row stride;
// legal since global_load_lds pins only the LDS DEST order, not the source.
// Epilogue: exp + row sums (+ col sums for off-diagonal blocks).
// ---------------------------------------------------------------------------
__device__ __forceinline__ void load_lds16(const bf16_t* g, bf16_t* l) {
    __builtin_amdgcn_global_load_lds(
        (const __attribute__((address_space(1))) unsigned int*)g,
        (__attribute__((address_space(3))) unsigned int*)l,
        16, 0, 0);
}

__global__ __launch_bounds__(256) void k_simgemm(const bf16_t* __restrict__ xn,
                                                 float* __restrict__ rowsum) {
    __shared__ bf16_t As[128 * 128];   // 32 KB
    __shared__ bf16_t Bs[128 * 128];   // 32 KB
    __shared__ float  rpA[128];
    __shared__ float  rpB[128];

    // unrank blockIdx.x -> (bm <= bn) upper-triangle pair
    const int t = blockIdx.x;
    int bn = (int)((sqrtf(8.0f * (float)t + 1.0f) - 1.0f) * 0.5f);
    while ((bn * (bn + 1)) / 2 > t) --bn;
    while (((bn + 1) * (bn + 2)) / 2 <= t) ++bn;
    const int bm = t - (bn * (bn + 1)) / 2;
    const bool diagb = (bm == bn);

    const int tid  = threadIdx.x;
    const int lane = tid & 63;
    const int wid  = tid >> 6;
    const int wr   = wid >> 1;   // wave row half
    const int wc   = wid & 1;    // wave col half
    const int q    = lane >> 4;
    const int l15  = lane & 15;

    if (tid < 128) { rpA[tid] = 0.0f; rpB[tid] = 0.0f; }

    // Staging: issue i of 8 covers rows i*16..i*16+15 of the tile, one
    // 128-wide k-chunk row slice. Thread t -> subrow t/16, chunk c=t%16.
    // LDS dest (fixed order): (i*16 + t/16)*128 + (t%16)*8  == base_i + t*8.
    // Global src chunk is XOR-swizzled: c ^ subrow.
    const int subrow = tid >> 4;         // 0..15
    const int chnk   = tid & 15;         // 0..15
    const int swz    = chnk ^ subrow;    // source k-chunk
    const bf16_t* gA = xn + (size_t)(bm * 128 + subrow) * DIM + swz * 8;
    const bf16_t* gB = xn + (size_t)(bn * 128 + subrow) * DIM + swz * 8;
    bf16_t* lA = &As[tid * 8];
    bf16_t* lB = &Bs[tid * 8];

    f32x4 acc[4][4] = {};

    for (int k0 = 0; k0 < DIM; k0 += 128) {
        __syncthreads();  // protect previous iteration's LDS reads
#pragma unroll
        for (int i = 0; i < 8; ++i) {
            load_lds16(gA + (size_t)(i * 16) * DIM + k0, lA + i * 2048);
            load_lds16(gB + (size_t)(i * 16) * DIM + k0, lB + i * 2048);
        }
        __syncthreads();  // drain vmcnt -> tiles visible

#pragma unroll
        for (int kb = 0; kb < 4; ++kb) {   // 4 x K=32 within the 128 chunk
            bf16x8 af[4], bfv[4];
#pragma unroll
            for (int mt = 0; mt < 4; ++mt) {
                const int row = wr * 64 + mt * 16 + l15;
                af[mt] = *reinterpret_cast<const bf16x8*>(
                    &As[row * 128 + ((kb * 4 + q) ^ l15) * 8]);
            }
#pragma unroll
            for (int nt = 0; nt < 4; ++nt) {
                const int row = wc * 64 + nt * 16 + l15;
                bfv[nt] = *reinterpret_cast<const bf16x8*>(
                    &Bs[row * 128 + ((kb * 4 + q) ^ l15) * 8]);
            }
#pragma unroll
            for (int mt = 0; mt < 4; ++mt)
#pragma unroll
                for (int nt = 0; nt < 4; ++nt)
                    acc[mt][nt] = __builtin_amdgcn_mfma_f32_16x16x32_bf16(
                        af[mt], bfv[nt], acc[mt][nt], 0, 0, 0);
        }
    }

    // Epilogue. C/D: row = wr*64+mt*16+q*4+r, col = wc*64+nt*16+l15.
    float colacc[4] = {0.0f, 0.0f, 0.0f, 0.0f};
#pragma unroll
    for (int mt = 0; mt < 4; ++mt) {
        float rowp[4] = {0.0f, 0.0f, 0.0f, 0.0f};
#pragma unroll
        for (int nt = 0; nt < 4; ++nt)
#pragma unroll
            for (int r = 0; r < 4; ++r) {
                float e = __expf(TEMP_INV * acc[mt][nt][r]);
                rowp[r] += e;
                colacc[nt] += e;
            }
#pragma unroll
        for (int r = 0; r < 4; ++r) {
            float p = rowp[r];
            p += __shfl_xor(p, 1, 64);
            p += __shfl_xor(p, 2, 64);
            p += __shfl_xor(p, 4, 64);
            p += __shfl_xor(p, 8, 64);
            if (l15 == 0) atomicAdd(&rpA[wr * 64 + mt * 16 + q * 4 + r], p);
        }
    }
    if (!diagb) {
#pragma unroll
        for (int nt = 0; nt < 4; ++nt) {
            float c = colacc[nt];
            c += __shfl_xor(c, 16, 64);
            c += __shfl_xor(c, 32, 64);
            if (q == 0) atomicAdd(&rpB[wc * 64 + nt * 16 + l15], c);
        }
    }
    __syncthreads();
    if (tid < 128) {
        atomicAdd(&rowsum[bm * 128 + tid], rpA[tid]);
    } else if (!diagb) {
        atomicAdd(&rowsum[bn * 128 + (tid - 128)], rpB[tid - 128]);
    }
}

// ---------------------------------------------------------------------------
// Kernel 3: loss = mean_i( log(S_i - exp(diag_i)) - pos_i )
// ---------------------------------------------------------------------------
__global__ __launch_bounds__(256) void k_finalize(const float* __restrict__ rowsum,
                                                  const float* __restrict__ pos,
                                                  const float* __restrict__ diag,
                                                  float* __restrict__ out) {
    __shared__ float red[256];
    float s = 0.0f;
    for (int i = threadIdx.x; i < N2; i += 256)
        s += __logf(rowsum[i] - __expf(diag[i])) - pos[i];
    red[threadIdx.x] = s;
    __syncthreads();
    for (int st = 128; st; st >>= 1) {
        if (threadIdx.x < st) red[threadIdx.x] += red[threadIdx.x + st];
        __syncthreads();
    }
    if (threadIdx.x == 0) out[0] = red[0] / (float)N2;
}

// ---------------------------------------------------------------------------
extern "C" void kernel_launch(void* const* d_in, const int* in_sizes, int n_in,
                              void* d_out, int out_size, void* d_ws, size_t ws_size,
                              hipStream_t stream) {
    (void)in_sizes; (void)n_in; (void)out_size; (void)ws_size;
    const float* x = (const float*)d_in[0];
    float* out = (float*)d_out;

    char* ws = (char*)d_ws;
    bf16_t* xn     = (bf16_t*)ws;                          // 4 MB
    float*  rowsum = (float*)(ws + (size_t)N2 * DIM * 2);  // 16 KB
    float*  pos    = rowsum + N2;
    float*  diag   = pos + N2;

    k_prep<<<512, 256, 0, stream>>>(x, xn, pos, diag, rowsum);
    k_simgemm<<<528, 256, 0, stream>>>(xn, rowsum);
    k_finalize<<<1, 256, 0, stream>>>(rowsum, pos, diag, out);
}